// Round 2
// baseline (108.484 us; speedup 1.0000x reference)
//
#include <hip/hip_runtime.h>
#include <hip/hip_bf16.h>
#include <stdint.h>
#include <stddef.h>

// NT-Xent loss, B=4096, D=256, N=8192, T=0.5.
// normalize(+zero sumexp) -> fused symmetric ZZ^T GEMM + exp row/col-sum +
// positive capture -> 1-block finalize/mean. No NxN materialization.
//
// R9 (resubmit; R1 bench was a GPUAcquisitionTimeout, no data):
// DROP LDS STAGING (common-mistake #7: zn is 4 MB -> L2-resident per
// XCD; staging through LDS + per-iter __syncthreads/vmcnt(0) drain was the
// 2-phase ~72%-overhead signature, ~20% MfmaUtil vs the 8.4 us MFMA floor).
// B fragments now load straight from global (L2 hit) with a depth-4
// register pipeline (p0..p3, 32 VGPRs) over the kq loop; zero barriers,
// zero LDS, waves fully independent. Also balances the tail: the s=32
// positive tile-pair is split between cj=6 (subtile 0) and cj=7 (subtile 1)
// so every block runs <=9 iterations (was 10 vs 8 -> +25% critical path).
// R8 carry-overs: symmetry (each unordered 128x128 tile-pair once: row-sums
// to rows(ri), col-sums to rows(ct); 2080 tiles), register-resident full-D
// A fragments, __builtin_amdgcn_exp2f epilogue, positive capture in s=32.

#define B_ROWS 4096
#define D_DIM  256
#define N_ROWS 8192
#define BM 128
#define BN 64

typedef __bf16 bf16;
typedef bf16  bf16x8  __attribute__((ext_vector_type(8)));
typedef bf16  bf16x4  __attribute__((ext_vector_type(4)));
typedef float floatx4 __attribute__((ext_vector_type(4)));

// ---------------------------------------------------------------- normalize
// One wave per row: 256 fp32 -> L2-normalized bf16. Also zeroes sumexp[row].
__global__ __launch_bounds__(256) void normalize_kernel(
    const float* __restrict__ z_i, const float* __restrict__ z_j,
    bf16* __restrict__ zn, float* __restrict__ sumexp) {
  const int wave = threadIdx.x >> 6;
  const int lane = threadIdx.x & 63;
  const int row  = blockIdx.x * 4 + wave;
  const float* src = (row < B_ROWS) ? (z_i + (size_t)row * D_DIM)
                                    : (z_j + (size_t)(row - B_ROWS) * D_DIM);
  float4 v = ((const float4*)src)[lane];
  float ss = v.x * v.x + v.y * v.y + v.z * v.z + v.w * v.w;
  #pragma unroll
  for (int m = 1; m < 64; m <<= 1) ss += __shfl_xor(ss, m);
  const float rn = rsqrtf(ss);
  bf16x4 o;
  o[0] = (bf16)(v.x * rn);
  o[1] = (bf16)(v.y * rn);
  o[2] = (bf16)(v.z * rn);
  o[3] = (bf16)(v.w * rn);
  ((bf16x4*)(zn + (size_t)row * D_DIM))[lane] = o;
  if (lane == 0) sumexp[row] = 0.f;
}

// ------------------------------------------------------- fused sim+exp+sum
// Grid: 64 ri x 8 cj = 512 blocks (2/CU, VGPR-bound). Block (ri,cj) handles
// tile-pairs s = 4cj+p, p=0..3; for ri<32, cj==6 additionally takes subtile
// 0 of s=32 and cj==7 subtile 1 -> 8 or 9 iterations per block. 4 waves in
// 2x2; wave = 64 rows x 32 cols = 4x2 frags of 16x16x32 bf16 MFMA, full-D
// accumulate. B fragments are read directly from global memory (zn is 4 MB,
// L2-resident after first touch per XCD) -- no LDS, no __syncthreads.
__global__ __launch_bounds__(256, 2) void simexp_kernel(
    const bf16* __restrict__ zn, float* __restrict__ sumexp,
    float* __restrict__ pos) {
  const int tid   = threadIdx.x;
  const int wave  = tid >> 6;
  const int lane  = tid & 63;
  const int lcol  = lane & 15;   // MFMA: A row / B col / C col
  const int lquad = lane >> 4;   // MFMA: k-group / C row-group
  const int wr = (wave >> 1) * 64;  // wave row offset in 128
  const int wc = (wave & 1) * 32;   // wave col offset in 64
  const int ri = blockIdx.x >> 3;   // row tile 0..63
  const int cj = blockIdx.x & 7;    // s-chunk 0..7
  const int row_base = ri * BM;
  const int niter = (ri < 32 && cj >= 6) ? 9 : 8;

  // A fragments, register-resident for the whole block (8-9x reuse).
  // af[ti][kq]: row = row_base+wr+ti*16+lcol, k = kq*32 + lquad*8 .. +7
  floatx4 af[4][8];
  #pragma unroll
  for (int ti = 0; ti < 4; ++ti) {
    const bf16* arow =
        zn + (size_t)(row_base + wr + ti * 16 + lcol) * D_DIM + lquad * 8;
    #pragma unroll
    for (int kq = 0; kq < 8; ++kq)
      af[ti][kq] = *(const floatx4*)(arow + kq * 32);
  }

  float rowsum[4][4];  // [ti][r]; row = wr + ti*16 + lquad*4 + r
  #pragma unroll
  for (int ti = 0; ti < 4; ++ti)
    #pragma unroll
    for (int r = 0; r < 4; ++r) rowsum[ti][r] = 0.f;

  #pragma unroll 1  // keep body small (I$); niter is dynamic anyway
  for (int t = 0; t < niter; ++t) {
    // iteration -> tile-pair s and 64-col subtile
    const int s   = (t == 8) ? 32 : 4 * cj + (t >> 1);
    const int sub = (t == 8) ? (cj - 6) : (t & 1);
    const int jt  = 2 * ((ri + s) & 63) + sub;   // j64-tile index 0..127
    const bf16* bb = zn + (size_t)jt * BN * D_DIM + lquad * 8;

    // B fragment for (KQ,TJ): col n = wc+TJ*16+lcol, k = KQ*32+lquad*8..+7
#define LDB(KQ, TJ) \
    (*(const bf16x8*)(bb + (size_t)(wc + (TJ)*16 + lcol) * D_DIM + (KQ)*32))

    floatx4 acc[4][2];
    #pragma unroll
    for (int ti = 0; ti < 4; ++ti)
      #pragma unroll
      for (int tj = 0; tj < 2; ++tj) acc[ti][tj] = floatx4{0.f, 0.f, 0.f, 0.f};

    // depth-4 software pipeline over kq: issue loads 4 k-quads ahead of the
    // MFMAs that consume them (~600 cyc lookahead >= L2 hit latency).
    // All indices static (macros) -> no scratch (rule #20).
    bf16x8 p0[2], p1[2], p2[2], p3[2];
    p0[0] = LDB(0, 0); p0[1] = LDB(0, 1);
    p1[0] = LDB(1, 0); p1[1] = LDB(1, 1);
    p2[0] = LDB(2, 0); p2[1] = LDB(2, 1);
    p3[0] = LDB(3, 0); p3[1] = LDB(3, 1);

#define MFQ(P, KQ)                                                          \
    {                                                                       \
      _Pragma("unroll")                                                     \
      for (int ti = 0; ti < 4; ++ti) {                                      \
        acc[ti][0] = __builtin_amdgcn_mfma_f32_16x16x32_bf16(               \
            __builtin_bit_cast(bf16x8, af[ti][KQ]), P[0], acc[ti][0],       \
            0, 0, 0);                                                       \
        acc[ti][1] = __builtin_amdgcn_mfma_f32_16x16x32_bf16(               \
            __builtin_bit_cast(bf16x8, af[ti][KQ]), P[1], acc[ti][1],       \
            0, 0, 0);                                                       \
      }                                                                     \
    }

    MFQ(p0, 0) p0[0] = LDB(4, 0); p0[1] = LDB(4, 1);
    MFQ(p1, 1) p1[0] = LDB(5, 0); p1[1] = LDB(5, 1);
    MFQ(p2, 2) p2[0] = LDB(6, 0); p2[1] = LDB(6, 1);
    MFQ(p3, 3) p3[0] = LDB(7, 0); p3[1] = LDB(7, 1);
    MFQ(p0, 4)
    MFQ(p1, 5)
    MFQ(p2, 6)
    MFQ(p3, 7)
#undef MFQ
#undef LDB

    // epilogue: e = exp(sim/T) = exp(2*dot) = 2^(v * 2/ln2)
    const bool diag = (s == 0);
    const bool posT = (s == 32);
    const int col_base = jt * BN;
    float colsum[2] = {0.f, 0.f};
    #pragma unroll
    for (int ti = 0; ti < 4; ++ti) {
      #pragma unroll
      for (int tj = 0; tj < 2; ++tj) {
        #pragma unroll
        for (int r = 0; r < 4; ++r) {
          const float v = acc[ti][tj][r];
          float e = __builtin_amdgcn_exp2f(v * 2.8853900817779268f);
          if (diag || posT) {
            const int rg = row_base + wr + ti * 16 + lquad * 4 + r;
            const int cg = col_base + wc + tj * 16 + lcol;
            if (diag && cg == rg) e = 0.f;               // mask self
            if (posT && cg == rg + B_ROWS) {             // positive pair
              pos[rg] = 2.0f * v;
              pos[cg] = 2.0f * v;
            }
          }
          rowsum[ti][r] += e;
          colsum[tj]    += e;
        }
      }
    }

    // symmetric contribution: col-sums -> rows of the partner tile.
    // (skip on diag tile: both orientations already inside the tile)
    if (!diag) {
      #pragma unroll
      for (int tj = 0; tj < 2; ++tj) {
        float cs = colsum[tj];
        cs += __shfl_xor(cs, 16);
        cs += __shfl_xor(cs, 32);
        if (lquad == 0)
          atomicAdd(&sumexp[col_base + wc + tj * 16 + lcol], cs);
      }
    }
  }

  // reduce the 16 col-lanes of rowsum, then 1 atomic per row per wave
  #pragma unroll
  for (int ti = 0; ti < 4; ++ti) {
    #pragma unroll
    for (int r = 0; r < 4; ++r) {
      float s2 = rowsum[ti][r];
      s2 += __shfl_xor(s2, 1);
      s2 += __shfl_xor(s2, 2);
      s2 += __shfl_xor(s2, 4);
      s2 += __shfl_xor(s2, 8);
      if (lcol == 0) {
        const int grow = row_base + wr + ti * 16 + lquad * 4 + r;
        atomicAdd(&sumexp[grow], s2);
      }
    }
  }
}

// ------------------------------------------------- finalize + mean (1 block)
// loss_i = log(sumexp_i) - pos_i ; out = mean(loss)
__global__ __launch_bounds__(1024) void reduce_kernel(
    const float* __restrict__ sumexp, const float* __restrict__ pos,
    float* __restrict__ out) {
  __shared__ float ws[16];
  const int tid = threadIdx.x;
  float s = 0.f;
  const float ln2 = 0.6931471805599453f;
  for (int k = tid; k < N_ROWS; k += 1024)
    s += __builtin_amdgcn_logf(sumexp[k]) * ln2 - pos[k];
  #pragma unroll
  for (int m = 1; m < 64; m <<= 1) s += __shfl_xor(s, m);
  const int wave = tid >> 6, lane = tid & 63;
  if (lane == 0) ws[wave] = s;
  __syncthreads();
  if (wave == 0) {
    float t = (lane < 16) ? ws[lane] : 0.f;
    #pragma unroll
    for (int m = 1; m < 16; m <<= 1) t += __shfl_xor(t, m);
    if (lane == 0) out[0] = t * (1.0f / N_ROWS);
  }
}

extern "C" void kernel_launch(void* const* d_in, const int* in_sizes, int n_in,
                              void* d_out, int out_size, void* d_ws,
                              size_t ws_size, hipStream_t stream) {
  const float* z_i = (const float*)d_in[0];
  const float* z_j = (const float*)d_in[1];
  float* out = (float*)d_out;

  // workspace layout: zn (4 MB bf16) | sumexp (32 KB) | pos (32 KB)
  bf16* zn = (bf16*)d_ws;
  float* sumexp = (float*)((char*)d_ws + (size_t)N_ROWS * D_DIM * sizeof(bf16));
  float* pos = sumexp + N_ROWS;

  normalize_kernel<<<N_ROWS / 4, 256, 0, stream>>>(z_i, z_j, zn, sumexp);
  simexp_kernel<<<512, 256, 0, stream>>>(zn, sumexp, pos);
  reduce_kernel<<<1, 1024, 0, stream>>>(sumexp, pos, out);
}

// Round 3
// 108.255 us; speedup vs baseline: 1.0021x; 1.0021x over previous
//
#include <hip/hip_runtime.h>
#include <hip/hip_bf16.h>
#include <stdint.h>
#include <stddef.h>

// NT-Xent loss, B=4096, D=256, N=8192, T=0.5.
// normalize(+zero sumexp) -> fused symmetric ZZ^T GEMM + exp row/col-sum +
// positive capture -> 1-block finalize/mean. No NxN materialization.
//
// R10: R9's no-LDS plan was DEFEATED BY CODEGEN: VGPR_Count=120 proves the
// compiler targeted 4 waves/SIMD (useless: 512-block grid caps at 2
// blocks/CU = 2 waves/SIMD) and spilled/rematerialized the 128-VGPR A
// fragments into the loop (4 MB WRITE_SIZE = spill stores; MfmaUtil 13%,
// all pipes idle -> serialized L2-latency chain). Fix:
//  (a) amdgpu_waves_per_eu(2,2): pins the occupancy target, unlocking the
//      256-VGPR budget so af[4][8] stays register-resident; asm "+v"
//      keep-alive fences prevent load sinking/remat.
//  (b) cross-iteration two-group B pipeline: issue Q(t)=kq4..7 -> MFMA
//      P(t)=kq0..3 -> issue P(t+1) -> MFMA Q(t) -> epilogue(t). P(t+1)
//      hides under the ~400cyc exp epilogue; Q(t) under 4 MFMA clusters.
//      Peak regs ~245 < 256.
// Carry-overs: symmetry (each unordered 128x128 tile-pair once; 2080
// tiles), balanced tail (s=32 split cj6/cj7, <=9 iters), direct-global B
// (zn 4 MB = L2-resident), __builtin_amdgcn_exp2f epilogue.

#define B_ROWS 4096
#define D_DIM  256
#define N_ROWS 8192
#define BM 128
#define BN 64

typedef __bf16 bf16;
typedef bf16  bf16x8  __attribute__((ext_vector_type(8)));
typedef bf16  bf16x4  __attribute__((ext_vector_type(4)));
typedef float floatx4 __attribute__((ext_vector_type(4)));

// ---------------------------------------------------------------- normalize
// One wave per row: 256 fp32 -> L2-normalized bf16. Also zeroes sumexp[row].
__global__ __launch_bounds__(256) void normalize_kernel(
    const float* __restrict__ z_i, const float* __restrict__ z_j,
    bf16* __restrict__ zn, float* __restrict__ sumexp) {
  const int wave = threadIdx.x >> 6;
  const int lane = threadIdx.x & 63;
  const int row  = blockIdx.x * 4 + wave;
  const float* src = (row < B_ROWS) ? (z_i + (size_t)row * D_DIM)
                                    : (z_j + (size_t)(row - B_ROWS) * D_DIM);
  float4 v = ((const float4*)src)[lane];
  float ss = v.x * v.x + v.y * v.y + v.z * v.z + v.w * v.w;
  #pragma unroll
  for (int m = 1; m < 64; m <<= 1) ss += __shfl_xor(ss, m);
  const float rn = rsqrtf(ss);
  bf16x4 o;
  o[0] = (bf16)(v.x * rn);
  o[1] = (bf16)(v.y * rn);
  o[2] = (bf16)(v.z * rn);
  o[3] = (bf16)(v.w * rn);
  ((bf16x4*)(zn + (size_t)row * D_DIM))[lane] = o;
  if (lane == 0) sumexp[row] = 0.f;
}

// ------------------------------------------------------- fused sim+exp+sum
// Grid: 64 ri x 8 cj = 512 blocks (2/CU). Block (ri,cj) handles tile-pairs
// s = 4cj+p, p=0..3; for ri<32, cj==6 takes subtile 0 of s=32, cj==7
// subtile 1 -> 8 or 9 iterations. 4 waves in 2x2; wave = 64 rows x 32 cols
// = 4x2 frags of 16x16x32 bf16 MFMA, full-D accumulate. B direct-global.
__global__ __launch_bounds__(256)
__attribute__((amdgpu_waves_per_eu(2, 2)))
void simexp_kernel(
    const bf16* __restrict__ zn, float* __restrict__ sumexp,
    float* __restrict__ pos) {
  const int tid   = threadIdx.x;
  const int wave  = tid >> 6;
  const int lane  = tid & 63;
  const int lcol  = lane & 15;   // MFMA: A row / B col / C col
  const int lquad = lane >> 4;   // MFMA: k-group / C row-group
  const int wr = (wave >> 1) * 64;  // wave row offset in 128
  const int wc = (wave & 1) * 32;   // wave col offset in 64
  const int ri = blockIdx.x >> 3;   // row tile 0..63
  const int cj = blockIdx.x & 7;    // s-chunk 0..7
  const int row_base = ri * BM;
  const int niter = (ri < 32 && cj >= 6) ? 9 : 8;

  // iteration -> B j64-tile base pointer (includes lquad k-offset)
  auto tile_bb = [&](int t) {
    const int s   = (t == 8) ? 32 : 4 * cj + (t >> 1);
    const int sub = (t == 8) ? (cj - 6) : (t & 1);
    const int jt  = 2 * ((ri + s) & 63) + sub;   // j64-tile index 0..127
    return zn + (size_t)jt * BN * D_DIM + lquad * 8;
  };

  // A fragments, register-resident for the whole block (8-9x reuse).
  // af[ti][kq]: row = row_base+wr+ti*16+lcol, k = kq*32 + lquad*8 .. +7
  floatx4 af[4][8];
  #pragma unroll
  for (int ti = 0; ti < 4; ++ti) {
    const bf16* arow =
        zn + (size_t)(row_base + wr + ti * 16 + lcol) * D_DIM + lquad * 8;
    #pragma unroll
    for (int kq = 0; kq < 8; ++kq)
      af[ti][kq] = *(const floatx4*)(arow + kq * 32);
  }
  // keep-alive fence: values become opaque -> cannot be sunk/remat'd into
  // the loop; with the waves_per_eu(2,2) budget they stay in registers.
  #pragma unroll
  for (int ti = 0; ti < 4; ++ti)
    #pragma unroll
    for (int kq = 0; kq < 8; ++kq)
      asm volatile("" : "+v"(af[ti][kq]));

  float rowsum[4][4];  // [ti][r]; row = wr + ti*16 + lquad*4 + r
  #pragma unroll
  for (int ti = 0; ti < 4; ++ti)
    #pragma unroll
    for (int r = 0; r < 4; ++r) rowsum[ti][r] = 0.f;

  // B fragment for (KQ,TJ) at tile base BB:
  // col n = wc+TJ*16+lcol, k = KQ*32 + lquad*8 .. +7
#define LDB(BB, KQ, TJ) \
    (*(const bf16x8*)((BB) + (size_t)(wc + (TJ)*16 + lcol) * D_DIM + (KQ)*32))

#define MFQ(P, KQ)                                                          \
    {                                                                       \
      _Pragma("unroll")                                                     \
      for (int ti = 0; ti < 4; ++ti) {                                      \
        acc[ti][0] = __builtin_amdgcn_mfma_f32_16x16x32_bf16(               \
            __builtin_bit_cast(bf16x8, af[ti][KQ]), P[0], acc[ti][0],       \
            0, 0, 0);                                                       \
        acc[ti][1] = __builtin_amdgcn_mfma_f32_16x16x32_bf16(               \
            __builtin_bit_cast(bf16x8, af[ti][KQ]), P[1], acc[ti][1],       \
            0, 0, 0);                                                       \
      }                                                                     \
    }

  // prologue: group P = kq0..3 of iteration 0
  const bf16* bbc = tile_bb(0);
  bf16x8 p0[2], p1[2], p2[2], p3[2];
  bf16x8 q0[2], q1[2], q2[2], q3[2];
  p0[0] = LDB(bbc, 0, 0); p0[1] = LDB(bbc, 0, 1);
  p1[0] = LDB(bbc, 1, 0); p1[1] = LDB(bbc, 1, 1);
  p2[0] = LDB(bbc, 2, 0); p2[1] = LDB(bbc, 2, 1);
  p3[0] = LDB(bbc, 3, 0); p3[1] = LDB(bbc, 3, 1);

  #pragma unroll 1  // keep body small (I$); niter is dynamic anyway
  for (int t = 0; t < niter; ++t) {
    const int tn = (t + 1 < niter) ? t + 1 : t;  // clamp: dup loads harmless
    const bf16* bbn = tile_bb(tn);

    // issue Q(t) = kq4..7 (covered by the 4 P-MFMA clusters below)
    q0[0] = LDB(bbc, 4, 0); q0[1] = LDB(bbc, 4, 1);
    q1[0] = LDB(bbc, 5, 0); q1[1] = LDB(bbc, 5, 1);
    q2[0] = LDB(bbc, 6, 0); q2[1] = LDB(bbc, 6, 1);
    q3[0] = LDB(bbc, 7, 0); q3[1] = LDB(bbc, 7, 1);

    floatx4 acc[4][2];
    #pragma unroll
    for (int ti = 0; ti < 4; ++ti)
      #pragma unroll
      for (int tj = 0; tj < 2; ++tj) acc[ti][tj] = floatx4{0.f, 0.f, 0.f, 0.f};

    MFQ(p0, 0)
    MFQ(p1, 1)
    MFQ(p2, 2)
    MFQ(p3, 3)

    // issue P(t+1) = kq0..3 of next tile (covered by Q-MFMAs + epilogue)
    p0[0] = LDB(bbn, 0, 0); p0[1] = LDB(bbn, 0, 1);
    p1[0] = LDB(bbn, 1, 0); p1[1] = LDB(bbn, 1, 1);
    p2[0] = LDB(bbn, 2, 0); p2[1] = LDB(bbn, 2, 1);
    p3[0] = LDB(bbn, 3, 0); p3[1] = LDB(bbn, 3, 1);

    MFQ(q0, 4)
    MFQ(q1, 5)
    MFQ(q2, 6)
    MFQ(q3, 7)

    // epilogue: e = exp(sim/T) = exp(2*dot) = 2^(v * 2/ln2)
    const int s    = (t == 8) ? 32 : 4 * cj + (t >> 1);
    const int sub  = (t == 8) ? (cj - 6) : (t & 1);
    const int jt   = 2 * ((ri + s) & 63) + sub;
    const bool diag = (s == 0);
    const bool posT = (s == 32);
    const int col_base = jt * BN;
    float colsum[2] = {0.f, 0.f};
    #pragma unroll
    for (int ti = 0; ti < 4; ++ti) {
      #pragma unroll
      for (int tj = 0; tj < 2; ++tj) {
        #pragma unroll
        for (int r = 0; r < 4; ++r) {
          const float v = acc[ti][tj][r];
          float e = __builtin_amdgcn_exp2f(v * 2.8853900817779268f);
          if (diag || posT) {
            const int rg = row_base + wr + ti * 16 + lquad * 4 + r;
            const int cg = col_base + wc + tj * 16 + lcol;
            if (diag && cg == rg) e = 0.f;               // mask self
            if (posT && cg == rg + B_ROWS) {             // positive pair
              pos[rg] = 2.0f * v;
              pos[cg] = 2.0f * v;
            }
          }
          rowsum[ti][r] += e;
          colsum[tj]    += e;
        }
      }
    }

    // symmetric contribution: col-sums -> rows of the partner tile.
    // (skip on diag tile: both orientations already inside the tile)
    if (!diag) {
      #pragma unroll
      for (int tj = 0; tj < 2; ++tj) {
        float cs = colsum[tj];
        cs += __shfl_xor(cs, 16);
        cs += __shfl_xor(cs, 32);
        if (lquad == 0)
          atomicAdd(&sumexp[col_base + wc + tj * 16 + lcol], cs);
      }
    }

    bbc = bbn;
  }
#undef MFQ
#undef LDB

  // reduce the 16 col-lanes of rowsum, then 1 atomic per row per wave
  #pragma unroll
  for (int ti = 0; ti < 4; ++ti) {
    #pragma unroll
    for (int r = 0; r < 4; ++r) {
      float s2 = rowsum[ti][r];
      s2 += __shfl_xor(s2, 1);
      s2 += __shfl_xor(s2, 2);
      s2 += __shfl_xor(s2, 4);
      s2 += __shfl_xor(s2, 8);
      if (lcol == 0) {
        const int grow = row_base + wr + ti * 16 + lquad * 4 + r;
        atomicAdd(&sumexp[grow], s2);
      }
    }
  }
}

// ------------------------------------------------- finalize + mean (1 block)
// loss_i = log(sumexp_i) - pos_i ; out = mean(loss)
__global__ __launch_bounds__(1024) void reduce_kernel(
    const float* __restrict__ sumexp, const float* __restrict__ pos,
    float* __restrict__ out) {
  __shared__ float ws[16];
  const int tid = threadIdx.x;
  float s = 0.f;
  const float ln2 = 0.6931471805599453f;
  for (int k = tid; k < N_ROWS; k += 1024)
    s += __builtin_amdgcn_logf(sumexp[k]) * ln2 - pos[k];
  #pragma unroll
  for (int m = 1; m < 64; m <<= 1) s += __shfl_xor(s, m);
  const int wave = tid >> 6, lane = tid & 63;
  if (lane == 0) ws[wave] = s;
  __syncthreads();
  if (wave == 0) {
    float t = (lane < 16) ? ws[lane] : 0.f;
    #pragma unroll
    for (int m = 1; m < 16; m <<= 1) t += __shfl_xor(t, m);
    if (lane == 0) out[0] = t * (1.0f / N_ROWS);
  }
}

extern "C" void kernel_launch(void* const* d_in, const int* in_sizes, int n_in,
                              void* d_out, int out_size, void* d_ws,
                              size_t ws_size, hipStream_t stream) {
  const float* z_i = (const float*)d_in[0];
  const float* z_j = (const float*)d_in[1];
  float* out = (float*)d_out;

  // workspace layout: zn (4 MB bf16) | sumexp (32 KB) | pos (32 KB)
  bf16* zn = (bf16*)d_ws;
  float* sumexp = (float*)((char*)d_ws + (size_t)N_ROWS * D_DIM * sizeof(bf16));
  float* pos = sumexp + N_ROWS;

  normalize_kernel<<<N_ROWS / 4, 256, 0, stream>>>(z_i, z_j, zn, sumexp);
  simexp_kernel<<<512, 256, 0, stream>>>(zn, sumexp, pos);
  reduce_kernel<<<1, 1024, 0, stream>>>(sumexp, pos, out);
}

// Round 4
// 95.571 us; speedup vs baseline: 1.1351x; 1.1327x over previous
//
#include <hip/hip_runtime.h>
#include <hip/hip_bf16.h>
#include <stdint.h>
#include <stddef.h>

// NT-Xent loss, B=4096, D=256, N=8192, T=0.5.
// normalize(+zero sumexp) -> fused symmetric ZZ^T GEMM + exp row/col-sum +
// positive capture -> 1-block finalize/mean. No NxN materialization.
//
// R11: force A-fragment register residency via LDS BOUNCE. R9/R10 proved
// the compiler re-loads af[4][8] (128 VGPR) from global every iteration no
// matter what (VGPR_Count 120/128, FETCH 17 MB, 49 us latency-bound at 13%
// on every pipe); direct-global fragment loads are also TA-amplified (16
// strided 64B segments per load vs 4 coalesced lines). Fix: stage the
// 128x256 A tile into the two B buffers (coalesced global_load_lds),
// barrier, ds_read the 32 af fragments (XOR-swizzled, conflict-free),
// barrier, then reuse the buffers for the B pipeline. ds_reads whose LDS
// backing is later overwritten CANNOT be rematerialized -> af is
// structurally pinned in registers. Also folds the 2/ln2 exp scale into
// normalize (zn *= sqrt(2/ln2)): epilogue exp2(v) direct, pos = v*ln2.
// Carry-overs (R8 structure, proven best): B-LDS double-buffer with
// swizzle-on-source staging, one barrier per j64-tile, stage-early;
// symmetry (2080 unordered 128x128 tile-pairs: row-sums to rows(ri),
// col-sums to rows(ct)); balanced tail (s=32 split cj6/cj7, <=9 iters);
// __builtin_amdgcn_exp2f.

#define B_ROWS 4096
#define D_DIM  256
#define N_ROWS 8192
#define BM 128
#define BN 64

typedef __bf16 bf16;
typedef bf16  bf16x8  __attribute__((ext_vector_type(8)));
typedef bf16  bf16x4  __attribute__((ext_vector_type(4)));
typedef float floatx4 __attribute__((ext_vector_type(4)));

// ---------------------------------------------------------------- normalize
// One wave per row: 256 fp32 -> L2-normalized bf16, pre-scaled by
// sqrt(2/ln2) so that dot' = (2/ln2)*dot and e = exp2(dot') directly.
// Also zeroes sumexp[row].
__global__ __launch_bounds__(256) void normalize_kernel(
    const float* __restrict__ z_i, const float* __restrict__ z_j,
    bf16* __restrict__ zn, float* __restrict__ sumexp) {
  const int wave = threadIdx.x >> 6;
  const int lane = threadIdx.x & 63;
  const int row  = blockIdx.x * 4 + wave;
  const float* src = (row < B_ROWS) ? (z_i + (size_t)row * D_DIM)
                                    : (z_j + (size_t)(row - B_ROWS) * D_DIM);
  float4 v = ((const float4*)src)[lane];
  float ss = v.x * v.x + v.y * v.y + v.z * v.z + v.w * v.w;
  #pragma unroll
  for (int m = 1; m < 64; m <<= 1) ss += __shfl_xor(ss, m);
  const float rn = rsqrtf(ss) * 1.6986436f;  // * sqrt(2/ln2)
  bf16x4 o;
  o[0] = (bf16)(v.x * rn);
  o[1] = (bf16)(v.y * rn);
  o[2] = (bf16)(v.z * rn);
  o[3] = (bf16)(v.w * rn);
  ((bf16x4*)(zn + (size_t)row * D_DIM))[lane] = o;
  if (lane == 0) sumexp[row] = 0.f;
}

// ------------------------------------------------------- fused sim+exp+sum
// Grid: 64 ri x 8 cj = 512 blocks (2/CU). Block (ri,cj) handles tile-pairs
// s = 4cj+p, p=0..3; for ri<32, cj==6 takes subtile 0 of s=32, cj==7
// subtile 1 -> 8 or 9 iterations. 4 waves in 2x2; wave = 64 rows x 32 cols
// = 4x2 frags of 16x16x32 bf16 MFMA, full-D accumulate.
// LDS layout XOR-swizzled (conflict-free): 16B chunk of row n, k-chunk kc
// lives at slot n*32 + ((kc&24)|((kc&7)^(n&7))); swizzle applied on the
// GLOBAL source address (global_load_lds dest must stay linear).
__global__ __launch_bounds__(256, 2) void simexp_kernel(
    const bf16* __restrict__ zn, float* __restrict__ sumexp,
    float* __restrict__ pos) {
  __shared__ __align__(16) bf16 Bs[2][BN * D_DIM];  // 2 x 32 KB

  const int tid   = threadIdx.x;
  const int wave  = tid >> 6;
  const int lane  = tid & 63;
  const int lcol  = lane & 15;   // MFMA: A row / B col / C col
  const int lquad = lane >> 4;   // MFMA: k-group / C row-group
  const int wr = (wave >> 1) * 64;  // wave row offset in 128
  const int wc = (wave & 1) * 32;   // wave col offset in 64
  const int ri = blockIdx.x >> 3;   // row tile 0..63
  const int cj = blockIdx.x & 7;    // s-chunk 0..7
  const int row_base = ri * BM;
  const int niter = (ri < 32 && cj >= 6) ? 9 : 8;

  // iteration -> B j64-tile index (0..127)
  auto jt64 = [&](int t) {
    const int s   = (t == 8) ? 32 : 4 * cj + (t >> 1);
    const int sub = (t == 8) ? (cj - 6) : (t & 1);
    return 2 * ((ri + s) & 63) + sub;
  };

  // stage a 64-row x 256-k bf16 tile at src into buffer buf
  // (8 x global_load_lds 16B per thread, coalesced, source pre-swizzled)
  auto stage = [&](int buf, const bf16* src) {
    #pragma unroll
    for (int it = 0; it < 8; ++it) {
      const int s   = it * 256 + tid;   // chunk slot 0..2047
      const int n   = s >> 5;           // row 0..63
      const int kcs = s & 31;           // swizzled k-chunk slot
      const int kc  = (kcs & 24) | ((kcs & 7) ^ (n & 7));
      __builtin_amdgcn_global_load_lds(
          (const __attribute__((address_space(1))) unsigned int*)
              (src + (size_t)n * D_DIM + kc * 8),
          (__attribute__((address_space(3))) unsigned int*)&Bs[buf][s * 8],
          16, 0, 0);
    }
  };

  // ---- A bounce: stage the 128x256 A tile into both buffers, read the af
  // fragments out, then the buffers are reused for the B pipeline. The
  // later staging writes alias the LDS -> compiler cannot remat/sink these
  // ds_reads -> af is pinned in registers for the whole kernel.
  stage(0, zn + (size_t)row_base * D_DIM);          // rows 0..63
  stage(1, zn + (size_t)(row_base + 64) * D_DIM);   // rows 64..127
  __syncthreads();  // drains vmcnt: both halves staged

  // af[ti][kq]: row = row_base+wr+ti*16+lcol, k = kq*32 + lquad*8 .. +7
  floatx4 af[4][8];
  {
    const int half = wr >> 6;  // wave rows 0-63 -> buf0, 64-127 -> buf1
    #pragma unroll
    for (int ti = 0; ti < 4; ++ti) {
      const int n = ti * 16 + lcol;
      #pragma unroll
      for (int kq = 0; kq < 8; ++kq) {
        const int kc  = kq * 4 + lquad;
        const int kcs = (kc & 24) | ((kc & 7) ^ (n & 7));
        af[ti][kq] = *(const floatx4*)(&Bs[half][(n * 32 + kcs) * 8]);
      }
    }
  }
  __syncthreads();  // all af reads done -> buffers free for B staging

  stage(0, zn + (size_t)jt64(0) * BN * D_DIM);  // first B prefetch

  float rowsum[4][4];  // [ti][r]; row = wr + ti*16 + lquad*4 + r
  #pragma unroll
  for (int ti = 0; ti < 4; ++ti)
    #pragma unroll
    for (int r = 0; r < 4; ++r) rowsum[ti][r] = 0.f;

  #pragma unroll 1  // keep body small (I$); niter is dynamic anyway
  for (int t = 0; t < niter; ++t) {
    __syncthreads();  // drains prefetch for buf[t&1]; fences other-buf reads
    if (t + 1 < niter) stage((t + 1) & 1, zn + (size_t)jt64(t + 1) * BN * D_DIM);

    floatx4 acc[4][2];
    #pragma unroll
    for (int ti = 0; ti < 4; ++ti)
      #pragma unroll
      for (int tj = 0; tj < 2; ++tj) acc[ti][tj] = floatx4{0.f, 0.f, 0.f, 0.f};

    const bf16* bbase = &Bs[t & 1][0];
    #pragma unroll
    for (int kq = 0; kq < 8; ++kq) {
      const int kc  = kq * 4 + lquad;
      bf16x8 bfr[2];
      #pragma unroll
      for (int tj = 0; tj < 2; ++tj) {
        const int n   = wc + tj * 16 + lcol;
        const int kcs = (kc & 24) | ((kc & 7) ^ (n & 7));
        bfr[tj] = *(const bf16x8*)(bbase + n * D_DIM + kcs * 8);
      }
      #pragma unroll
      for (int ti = 0; ti < 4; ++ti)
        #pragma unroll
        for (int tj = 0; tj < 2; ++tj)
          acc[ti][tj] = __builtin_amdgcn_mfma_f32_16x16x32_bf16(
              __builtin_bit_cast(bf16x8, af[ti][kq]), bfr[tj], acc[ti][tj],
              0, 0, 0);
    }

    // epilogue: v = dot' = (2/ln2)*dot -> e = exp(sim/T) = 2^v
    const int s    = (t == 8) ? 32 : 4 * cj + (t >> 1);
    const bool diag = (s == 0);
    const bool posT = (s == 32);
    const int jt = jt64(t);
    const int col_base = jt * BN;
    float colsum[2] = {0.f, 0.f};
    #pragma unroll
    for (int ti = 0; ti < 4; ++ti) {
      #pragma unroll
      for (int tj = 0; tj < 2; ++tj) {
        #pragma unroll
        for (int r = 0; r < 4; ++r) {
          const float v = acc[ti][tj][r];
          float e = __builtin_amdgcn_exp2f(v);
          if (diag || posT) {
            const int rg = row_base + wr + ti * 16 + lquad * 4 + r;
            const int cg = col_base + wc + tj * 16 + lcol;
            if (diag && cg == rg) e = 0.f;               // mask self
            if (posT && cg == rg + B_ROWS) {             // positive pair
              const float p = v * 0.6931471805599453f;   // sim/T = v*ln2
              pos[rg] = p;
              pos[cg] = p;
            }
          }
          rowsum[ti][r] += e;
          colsum[tj]    += e;
        }
      }
    }

    // symmetric contribution: col-sums -> rows of the partner tile.
    // (skip on diag tile: both orientations already inside the tile)
    if (!diag) {
      #pragma unroll
      for (int tj = 0; tj < 2; ++tj) {
        float cs = colsum[tj];
        cs += __shfl_xor(cs, 16);
        cs += __shfl_xor(cs, 32);
        if (lquad == 0)
          atomicAdd(&sumexp[col_base + wc + tj * 16 + lcol], cs);
      }
    }
  }

  // reduce the 16 col-lanes of rowsum, then 1 atomic per row per wave
  #pragma unroll
  for (int ti = 0; ti < 4; ++ti) {
    #pragma unroll
    for (int r = 0; r < 4; ++r) {
      float s2 = rowsum[ti][r];
      s2 += __shfl_xor(s2, 1);
      s2 += __shfl_xor(s2, 2);
      s2 += __shfl_xor(s2, 4);
      s2 += __shfl_xor(s2, 8);
      if (lcol == 0) {
        const int grow = row_base + wr + ti * 16 + lquad * 4 + r;
        atomicAdd(&sumexp[grow], s2);
      }
    }
  }
}

// ------------------------------------------------- finalize + mean (1 block)
// loss_i = log(sumexp_i) - pos_i ; out = mean(loss)
__global__ __launch_bounds__(1024) void reduce_kernel(
    const float* __restrict__ sumexp, const float* __restrict__ pos,
    float* __restrict__ out) {
  __shared__ float ws[16];
  const int tid = threadIdx.x;
  float s = 0.f;
  const float ln2 = 0.6931471805599453f;
  for (int k = tid; k < N_ROWS; k += 1024)
    s += __builtin_amdgcn_logf(sumexp[k]) * ln2 - pos[k];
  #pragma unroll
  for (int m = 1; m < 64; m <<= 1) s += __shfl_xor(s, m);
  const int wave = tid >> 6, lane = tid & 63;
  if (lane == 0) ws[wave] = s;
  __syncthreads();
  if (wave == 0) {
    float t = (lane < 16) ? ws[lane] : 0.f;
    #pragma unroll
    for (int m = 1; m < 16; m <<= 1) t += __shfl_xor(t, m);
    if (lane == 0) out[0] = t * (1.0f / N_ROWS);
  }
}

extern "C" void kernel_launch(void* const* d_in, const int* in_sizes, int n_in,
                              void* d_out, int out_size, void* d_ws,
                              size_t ws_size, hipStream_t stream) {
  const float* z_i = (const float*)d_in[0];
  const float* z_j = (const float*)d_in[1];
  float* out = (float*)d_out;

  // workspace layout: zn (4 MB bf16) | sumexp (32 KB) | pos (32 KB)
  bf16* zn = (bf16*)d_ws;
  float* sumexp = (float*)((char*)d_ws + (size_t)N_ROWS * D_DIM * sizeof(bf16));
  float* pos = sumexp + N_ROWS;

  normalize_kernel<<<N_ROWS / 4, 256, 0, stream>>>(z_i, z_j, zn, sumexp);
  simexp_kernel<<<512, 256, 0, stream>>>(zn, sumexp, pos);
  reduce_kernel<<<1, 1024, 0, stream>>>(sumexp, pos, out);
}

// Round 5
// 92.549 us; speedup vs baseline: 1.1722x; 1.0327x over previous
//
#include <hip/hip_runtime.h>
#include <hip/hip_bf16.h>
#include <stdint.h>
#include <stddef.h>

// NT-Xent loss, B=4096, D=256, N=8192, T=0.5.
// normalize(+zero sumexp) -> fused symmetric ZZ^T GEMM + exp row/col-sum +
// positive capture -> 1-block finalize/mean. No NxN materialization.
//
// R12: 8-WAVE 128x128 TILES + m201-STYLE PHASE SCHEDULE. R11 (95.6 us,
// simexp ~36 us) sits at the 2-phase stage->barrier->compute bound (m233:
// ~28% of MFMA-only; we measure ~23%). Port the proven escape at matched
// geometry (m201: 8-wave, 64KB tile, 16 MFMA/phase, 2-4 gloads/phase;
// m232 warns 4-wave 128^2 does NOT reproduce): 512 threads, 2x64KB LDS
// double-buffer (1 block/CU), per tile 4 phases of {ds_read 4xb128 ||
// issue 4x global_load_lds -> s_barrier -> lgkmcnt(0)+sched_barrier ->
// setprio(1) 16 MFMA setprio(0) -> s_barrier}, vmcnt(0) ONCE per tile at
// phase-3 end (stage loads are ~2 phases old there; atomics older).
// 8 uniform 128^2 tiles/block + half-tile tail for s=32 (split cj2/cj3,
// wall +5%); pos logic lives only in the tail.
// Carry-overs: A-bounce through LDS (R11's win: af[4][8] pinned in regs,
// now staged overlapped with B(0)); XOR-swizzled conflict-free LDS;
// symmetry (2080 unordered 128^2 tile-pairs; row-sums to rows(ri),
// col-sums to rows(ct), diag s=0 row-only); exp-scale folded into
// normalize (zn *= sqrt(2/ln2)): e = exp2(dot'), pos = dot'*ln2.

#define B_ROWS 4096
#define D_DIM  256
#define N_ROWS 8192
#define BM 128
#define BN 128

typedef __bf16 bf16;
typedef bf16  bf16x8  __attribute__((ext_vector_type(8)));
typedef bf16  bf16x4  __attribute__((ext_vector_type(4)));
typedef float floatx4 __attribute__((ext_vector_type(4)));

// ---------------------------------------------------------------- normalize
// One wave per row: 256 fp32 -> L2-normalized bf16, pre-scaled by
// sqrt(2/ln2) so dot' = (2/ln2)*dot and e = exp2(dot'). Zeroes sumexp.
__global__ __launch_bounds__(256) void normalize_kernel(
    const float* __restrict__ z_i, const float* __restrict__ z_j,
    bf16* __restrict__ zn, float* __restrict__ sumexp) {
  const int wave = threadIdx.x >> 6;
  const int lane = threadIdx.x & 63;
  const int row  = blockIdx.x * 4 + wave;
  const float* src = (row < B_ROWS) ? (z_i + (size_t)row * D_DIM)
                                    : (z_j + (size_t)(row - B_ROWS) * D_DIM);
  float4 v = ((const float4*)src)[lane];
  float ss = v.x * v.x + v.y * v.y + v.z * v.z + v.w * v.w;
  #pragma unroll
  for (int m = 1; m < 64; m <<= 1) ss += __shfl_xor(ss, m);
  const float rn = rsqrtf(ss) * 1.6986436f;  // * sqrt(2/ln2)
  bf16x4 o;
  o[0] = (bf16)(v.x * rn);
  o[1] = (bf16)(v.y * rn);
  o[2] = (bf16)(v.z * rn);
  o[3] = (bf16)(v.w * rn);
  ((bf16x4*)(zn + (size_t)row * D_DIM))[lane] = o;
  if (lane == 0) sumexp[row] = 0.f;
}

// ------------------------------------------------------- fused sim+exp+sum
// Grid: 64 ri x 4 cj = 256 blocks (1/CU). Block (ri,cj): 8 tiles s=8cj+t,
// t=0..7; blocks (ri<32, cj>=2) add the j64-half (cj-2) of the s=32 tile.
// 8 waves in 2x4; wave = 64 rows x 32 cols = 4x2 frags of 16x16x32 bf16
// MFMA, full-D accumulate. LDS XOR-swizzled (16B chunk of row n, k-chunk
// kc at slot n*32 + ((kc&24)|((kc&7)^(n&7))); swizzle on the GLOBAL source
// address, LDS dest linear).
__global__ __launch_bounds__(512, 2) void simexp_kernel(
    const bf16* __restrict__ zn, float* __restrict__ sumexp,
    float* __restrict__ pos) {
  __shared__ __align__(16) bf16 Bs[2][BN * D_DIM];  // 2 x 64 KB

  const int tid   = threadIdx.x;
  const int wave  = tid >> 6;
  const int lane  = tid & 63;
  const int lcol  = lane & 15;   // MFMA: A row / B col / C col
  const int lquad = lane >> 4;   // MFMA: k-group / C row-group
  const int wr = (wave >> 2) * 64;  // wave row offset in 128
  const int wc = (wave & 3) * 32;   // wave col offset in 128
  const int ri = blockIdx.x >> 2;   // row tile 0..63
  const int cj = blockIdx.x & 3;    // s-chunk 0..3
  const int row_base = ri * BM;
  const bool has_tail = (ri < 32 && cj >= 2);

  auto ct_of = [&](int t) { return (ri + 8 * cj + t) & 63; };  // col tile

  // stage rows of a tile into Bs[buf]: chunk slot s=it*512+tid, row n=s>>5,
  // swizzled k-chunk kc; 16B global_load_lds, coalesced, source-swizzled.
  auto stageB = [&](int buf, const bf16* src, int it0, int it1) {
    for (int it = it0; it < it1; ++it) {
      const int s   = it * 512 + tid;
      const int n   = s >> 5;
      const int kcs = s & 31;
      const int kc  = (kcs & 24) | ((kcs & 7) ^ (n & 7));
      __builtin_amdgcn_global_load_lds(
          (const __attribute__((address_space(1))) unsigned int*)
              (src + (size_t)n * D_DIM + kc * 8),
          (__attribute__((address_space(3))) unsigned int*)&Bs[buf][s * 8],
          16, 0, 0);
    }
  };

  // ---- prologue: A tile -> buf0, first B tile -> buf1, overlapped.
  stageB(0, zn + (size_t)row_base * D_DIM, 0, 8);
  stageB(1, zn + (size_t)ct_of(0) * BM * D_DIM, 0, 8);
  __syncthreads();  // drains vmcnt(0): both tiles resident

  // af[ti][kq] from buf0 (ds_reads whose backing is later overwritten ->
  // pinned in registers; R11's proven residency mechanism).
  floatx4 af[4][8];
  #pragma unroll
  for (int ti = 0; ti < 4; ++ti) {
    const int n = wr + ti * 16 + lcol;
    #pragma unroll
    for (int kq = 0; kq < 8; ++kq) {
      const int kc  = kq * 4 + lquad;
      const int kcs = (kc & 24) | ((kc & 7) ^ (n & 7));
      af[ti][kq] = *(const floatx4*)(&Bs[0][(n * 32 + kcs) * 8]);
    }
  }
  __syncthreads();  // all af reads done -> buf0 free for staging

  float rowsum[4][4];  // [ti][r]; row = wr + ti*16 + lquad*4 + r
  #pragma unroll
  for (int ti = 0; ti < 4; ++ti)
    #pragma unroll
    for (int r = 0; r < 4; ++r) rowsum[ti][r] = 0.f;

  // phase: ds_read 2 kq x 2 tj, issue stage slice, barrier, lgkm, 16 MFMA.
#define MFMA_(A, B_, C) __builtin_amdgcn_mfma_f32_16x16x32_bf16( \
    __builtin_bit_cast(bf16x8, A), B_, C, 0, 0, 0)
#define PHASE(KQA, KQB, IT0, IT1, DO_VM)                                  \
  {                                                                       \
    bf16x8 bfrA[2], bfrB[2];                                              \
    const int kcA = (KQA) * 4 + lquad, kcB = (KQB) * 4 + lquad;           \
    _Pragma("unroll")                                                     \
    for (int tj = 0; tj < 2; ++tj) {                                      \
      const int n  = wc + tj * 16 + lcol;                                 \
      const int sA = (kcA & 24) | ((kcA & 7) ^ (n & 7));                  \
      const int sB = (kcB & 24) | ((kcB & 7) ^ (n & 7));                  \
      bfrA[tj] = *(const bf16x8*)(bbase + n * D_DIM + sA * 8);            \
      bfrB[tj] = *(const bf16x8*)(bbase + n * D_DIM + sB * 8);            \
    }                                                                     \
    stageB(sb, nsrc, IT0, IT1);                                           \
    __builtin_amdgcn_sched_barrier(0);                                    \
    __builtin_amdgcn_s_barrier();                                         \
    asm volatile("s_waitcnt lgkmcnt(0)" ::: "memory");                    \
    __builtin_amdgcn_sched_barrier(0);                                    \
    __builtin_amdgcn_s_setprio(1);                                        \
    _Pragma("unroll")                                                     \
    for (int ti = 0; ti < 4; ++ti) {                                      \
      acc[ti][0] = MFMA_(af[ti][KQA], bfrA[0], acc[ti][0]);               \
      acc[ti][1] = MFMA_(af[ti][KQA], bfrA[1], acc[ti][1]);               \
    }                                                                     \
    _Pragma("unroll")                                                     \
    for (int ti = 0; ti < 4; ++ti) {                                      \
      acc[ti][0] = MFMA_(af[ti][KQB], bfrB[0], acc[ti][0]);               \
      acc[ti][1] = MFMA_(af[ti][KQB], bfrB[1], acc[ti][1]);               \
    }                                                                     \
    __builtin_amdgcn_s_setprio(0);                                        \
    if (DO_VM) asm volatile("s_waitcnt vmcnt(0)" ::: "memory");           \
    __builtin_amdgcn_sched_barrier(0);                                    \
    __builtin_amdgcn_s_barrier();                                         \
  }

  #pragma unroll 1  // one body copy (I$)
  for (int t = 0; t < 8; ++t) {
    const int cb = (t ^ 1) & 1;   // compute buffer (t=0 -> buf1)
    const int sb = cb ^ 1;        // stage buffer (tile t+1 / tail)
    const bf16* bbase = &Bs[cb][0];
    const bf16* nsrc = nullptr;
    int nl = 0;                   // stage loads this tile (per thread)
    if (t < 7) {
      nsrc = zn + (size_t)ct_of(t + 1) * BM * D_DIM;
      nl = 8;
    } else if (has_tail) {
      nsrc = zn + (size_t)((ri + 32) * BM + (cj - 2) * 64) * D_DIM;
      nl = 4;
    }
    const int nh = nl >> 1;

    floatx4 acc[4][2];
    #pragma unroll
    for (int ti = 0; ti < 4; ++ti)
      #pragma unroll
      for (int tj = 0; tj < 2; ++tj) acc[ti][tj] = floatx4{0.f, 0.f, 0.f, 0.f};

    PHASE(0, 1, 0, nh, false)
    PHASE(2, 3, nh, nl, false)
    PHASE(4, 5, 0, 0, false)
    PHASE(6, 7, 0, 0, true)   // vmcnt(0): stage loads ~2 phases old

    // epilogue: e = exp(sim/T) = 2^v (scale pre-folded into zn)
    const bool diag = (cj == 0 && t == 0);  // s == 0
    const int col_base = ct_of(t) * BM;
    float colsum[2] = {0.f, 0.f};
    #pragma unroll
    for (int ti = 0; ti < 4; ++ti) {
      #pragma unroll
      for (int tj = 0; tj < 2; ++tj) {
        #pragma unroll
        for (int r = 0; r < 4; ++r) {
          const float v = acc[ti][tj][r];
          float e = __builtin_amdgcn_exp2f(v);
          if (diag) {
            const int rg = row_base + wr + ti * 16 + lquad * 4 + r;
            const int cg = col_base + wc + tj * 16 + lcol;
            if (cg == rg) e = 0.f;  // mask self-similarity
          }
          rowsum[ti][r] += e;
          colsum[tj]    += e;
        }
      }
    }
    if (!diag) {  // col-sums -> rows of partner tile (diag: already rows)
      #pragma unroll
      for (int tj = 0; tj < 2; ++tj) {
        float cs = colsum[tj];
        cs += __shfl_xor(cs, 16);
        cs += __shfl_xor(cs, 32);
        if (lquad == 0)
          atomicAdd(&sumexp[col_base + wc + tj * 16 + lcol], cs);
      }
    }
  }

  // ---- tail: j64-half (cj-2) of the s=32 tile, buf1, no barriers needed
  // (buffer drained+synced at t=7 phase 3; never rewritten). Positive
  // pairs live exactly here: cg == rg + B_ROWS.
  if (has_tail && wc < 64) {
    const int h = cj - 2;
    const int col_base = (ri + 32) * BM + h * 64;
    const bf16* bbase = &Bs[1][0];
    floatx4 acc[4][2];
    #pragma unroll
    for (int ti = 0; ti < 4; ++ti)
      #pragma unroll
      for (int tj = 0; tj < 2; ++tj) acc[ti][tj] = floatx4{0.f, 0.f, 0.f, 0.f};
    #pragma unroll
    for (int kq = 0; kq < 8; ++kq) {
      const int kc = kq * 4 + lquad;
      bf16x8 bfr[2];
      #pragma unroll
      for (int tj = 0; tj < 2; ++tj) {
        const int n   = wc + tj * 16 + lcol;  // 0..63: staged rows
        const int kcs = (kc & 24) | ((kc & 7) ^ (n & 7));
        bfr[tj] = *(const bf16x8*)(bbase + n * D_DIM + kcs * 8);
      }
      #pragma unroll
      for (int ti = 0; ti < 4; ++ti) {
        acc[ti][0] = MFMA_(af[ti][kq], bfr[0], acc[ti][0]);
        acc[ti][1] = MFMA_(af[ti][kq], bfr[1], acc[ti][1]);
      }
    }
    float colsum[2] = {0.f, 0.f};
    #pragma unroll
    for (int ti = 0; ti < 4; ++ti) {
      #pragma unroll
      for (int tj = 0; tj < 2; ++tj) {
        #pragma unroll
        for (int r = 0; r < 4; ++r) {
          const float v = acc[ti][tj][r];
          const float e = __builtin_amdgcn_exp2f(v);
          const int rg = row_base + wr + ti * 16 + lquad * 4 + r;
          const int cg = col_base + wc + tj * 16 + lcol;
          if (cg == rg + B_ROWS) {               // positive pair
            const float p = v * 0.6931471805599453f;  // sim/T = v*ln2
            pos[rg] = p;
            pos[cg] = p;
          }
          rowsum[ti][r] += e;
          colsum[tj]    += e;
        }
      }
    }
    #pragma unroll
    for (int tj = 0; tj < 2; ++tj) {
      float cs = colsum[tj];
      cs += __shfl_xor(cs, 16);
      cs += __shfl_xor(cs, 32);
      if (lquad == 0)
        atomicAdd(&sumexp[col_base + wc + tj * 16 + lcol], cs);
    }
  }
#undef PHASE
#undef MFMA_

  // reduce the 16 col-lanes of rowsum, then 1 atomic per row per wave
  #pragma unroll
  for (int ti = 0; ti < 4; ++ti) {
    #pragma unroll
    for (int r = 0; r < 4; ++r) {
      float s2 = rowsum[ti][r];
      s2 += __shfl_xor(s2, 1);
      s2 += __shfl_xor(s2, 2);
      s2 += __shfl_xor(s2, 4);
      s2 += __shfl_xor(s2, 8);
      if (lcol == 0) {
        const int grow = row_base + wr + ti * 16 + lquad * 4 + r;
        atomicAdd(&sumexp[grow], s2);
      }
    }
  }
}

// ------------------------------------------------- finalize + mean (1 block)
// loss_i = log(sumexp_i) - pos_i ; out = mean(loss)
__global__ __launch_bounds__(1024) void reduce_kernel(
    const float* __restrict__ sumexp, const float* __restrict__ pos,
    float* __restrict__ out) {
  __shared__ float ws[16];
  const int tid = threadIdx.x;
  float s = 0.f;
  const float ln2 = 0.6931471805599453f;
  for (int k = tid; k < N_ROWS; k += 1024)
    s += __builtin_amdgcn_logf(sumexp[k]) * ln2 - pos[k];
  #pragma unroll
  for (int m = 1; m < 64; m <<= 1) s += __shfl_xor(s, m);
  const int wave = tid >> 6, lane = tid & 63;
  if (lane == 0) ws[wave] = s;
  __syncthreads();
  if (wave == 0) {
    float t = (lane < 16) ? ws[lane] : 0.f;
    #pragma unroll
    for (int m = 1; m < 16; m <<= 1) t += __shfl_xor(t, m);
    if (lane == 0) out[0] = t * (1.0f / N_ROWS);
  }
}

extern "C" void kernel_launch(void* const* d_in, const int* in_sizes, int n_in,
                              void* d_out, int out_size, void* d_ws,
                              size_t ws_size, hipStream_t stream) {
  const float* z_i = (const float*)d_in[0];
  const float* z_j = (const float*)d_in[1];
  float* out = (float*)d_out;

  // workspace layout: zn (4 MB bf16) | sumexp (32 KB) | pos (32 KB)
  bf16* zn = (bf16*)d_ws;
  float* sumexp = (float*)((char*)d_ws + (size_t)N_ROWS * D_DIM * sizeof(bf16));
  float* pos = sumexp + N_ROWS;

  normalize_kernel<<<N_ROWS / 4, 256, 0, stream>>>(z_i, z_j, zn, sumexp);
  simexp_kernel<<<256, 512, 0, stream>>>(zn, sumexp, pos);
  reduce_kernel<<<1, 1024, 0, stream>>>(sumexp, pos, out);
}